// Round 1
// baseline (114.997 us; speedup 1.0000x reference)
//
#include <hip/hip_runtime.h>

// GWD loss: pred(N,5) f32, target(N,5) f32, weight(N) f32 -> scalar mean.
// Closed-form per-row math (2x2 sym algebra collapsed), grid-stride +
// hierarchical reduction. FUN='log', TAU=1.0, ALPHA=1.0, LOSS_WEIGHT=1.0.

#define GWD_N 2000000

__global__ __launch_bounds__(256) void gwd_loss_kernel(
    const float* __restrict__ pred,
    const float* __restrict__ target,
    const float* __restrict__ weight,
    float* __restrict__ out,
    int n)
{
    const float inv_n = 1.0f / (float)n;
    float acc = 0.0f;

    const int stride = gridDim.x * blockDim.x;
    for (int i = blockIdx.x * blockDim.x + threadIdx.x; i < n; i += stride) {
        const int b = i * 5;
        // pred row
        const float px = pred[b + 0];
        const float py = pred[b + 1];
        const float pw = pred[b + 2];
        const float ph = pred[b + 3];
        const float pr = pred[b + 4];
        // target row
        const float tx = target[b + 0];
        const float ty = target[b + 1];
        const float tw = target[b + 2];
        const float th = target[b + 3];
        const float trr = target[b + 4];

        const float dx = px - tx;
        const float dy = py - ty;
        const float xy_dist = dx * dx + dy * dy;

        // a2 = (w/2)^2, b2 = (h/2)^2
        const float a2p = 0.25f * pw * pw;
        const float b2p = 0.25f * ph * ph;
        const float a2t = 0.25f * tw * tw;
        const float b2t = 0.25f * th * th;

        // trace(Sigma_p) + trace(Sigma_t)
        float whr = (a2p + b2p) + (a2t + b2t);

        float cp, sp, ct, st;
        __sincosf(pr, &sp, &cp);
        __sincosf(trr, &st, &ct);

        // Sigma = R diag(a2,b2) R^T
        const float Sp00 = cp * cp * a2p + sp * sp * b2p;
        const float Sp01 = cp * sp * (a2p - b2p);
        const float Sp11 = sp * sp * a2p + cp * cp * b2p;
        const float St00 = ct * ct * a2t + st * st * b2t;
        const float St01 = ct * st * (a2t - b2t);
        const float St11 = st * st * a2t + ct * ct * b2t;

        // tr(Sigma_p^(1/2) Sigma_t Sigma_p^(1/2)) = tr(Sigma_p Sigma_t)
        float tr_cross = Sp00 * St00 + 2.0f * Sp01 * St01 + Sp11 * St11;
        // det(cross) = det(Sigma_p) det(Sigma_t) = (a2p*b2p)*(a2t*b2t) >= 0
        float det_cross = (a2p * b2p) * (a2t * b2t);

        float sq = tr_cross + 2.0f * sqrtf(det_cross);
        sq = fmaxf(sq, 0.0f);
        const float sqrt_trace = sqrtf(sq);

        whr = whr - 2.0f * sqrt_trace;

        float dist2 = xy_dist + whr;           // ALPHA = 1
        dist2 = fmaxf(dist2, 0.0f);
        float distance = sqrtf(dist2);

        // scale = ((pw*tw)*(ph*th))^(1/4)
        const float prod = (pw * tw) * (ph * th);
        const float scale = sqrtf(sqrtf(prod));
        distance = distance / scale;

        // FUN == 'log'
        distance = log1pf(distance);

        // TAU = 1.0 >= 1.0
        const float loss = 1.0f - 1.0f / (1.0f + distance);

        acc += loss * weight[i];
    }

    // wave-64 reduction
    #pragma unroll
    for (int off = 32; off > 0; off >>= 1)
        acc += __shfl_down(acc, off, 64);

    __shared__ float wave_sums[4];   // 256 threads / 64 lanes
    const int lane = threadIdx.x & 63;
    const int wid  = threadIdx.x >> 6;
    if (lane == 0) wave_sums[wid] = acc;
    __syncthreads();

    if (threadIdx.x == 0) {
        const float s = (wave_sums[0] + wave_sums[1]) + (wave_sums[2] + wave_sums[3]);
        atomicAdd(out, s * inv_n);   // LOSS_WEIGHT = 1
    }
}

extern "C" void kernel_launch(void* const* d_in, const int* in_sizes, int n_in,
                              void* d_out, int out_size, void* d_ws, size_t ws_size,
                              hipStream_t stream) {
    const float* pred   = (const float*)d_in[0];
    const float* target = (const float*)d_in[1];
    const float* weight = (const float*)d_in[2];
    float* out = (float*)d_out;

    const int n = in_sizes[2];   // weight has N elements

    // harness poisons d_out with 0xAA before every timed launch
    hipMemsetAsync(out, 0, sizeof(float), stream);

    const int block = 256;
    const int grid = 1024;   // ~7.6 rows/thread; 1024 atomics total
    gwd_loss_kernel<<<grid, block, 0, stream>>>(pred, target, weight, out, n);
}